// Round 7
// baseline (274.927 us; speedup 1.0000x reference)
//
#include <hip/hip_runtime.h>

// SAGE layer: out = relu(x @ W_self + (segment_sum(x[src], dst)/max(deg,1)) @ W_neigh + b)
//
// R6 pipeline (7 dispatches, zero global atomics, no memsets on main path):
//   1. k_conv:   x->bf16 (2048 blocks) + W->bf16^T (WtG)
//   2. k_count:  block per 2048-edge chunk: LDS hist -> cnt[chunk][bucket] (plain stores)
//   3. k_scan:   1 block: per-bucket column scan of cnt (in-place -> per-chunk bases)
//                + LDS scan of totals -> bstart
//   4. k_place:  block per chunk: pos = bstart[b] + pref[c][b] + LDS-rank -> pay
//                (deterministic, no global cursor atomics)
//   5. k_csr:    block per bucket: exact per-row CSR + row_start (int LDS only)
//   6. k_aggregate: wave per dst row; 16 lanes/edge ushort4 gathers; shfl_xor reduce -> hb
//   7. k_gemm_mfma: A=[xb|hb] K=128, W from WtG, bias+relu (proven layout)
// Fallback (small ws): R0 atomic scatter + shfl gemm.

constexpr int F = 64;
constexpr int BROWS = 256;   // dst rows per bucket
constexpr int MAXNB = 512;   // max buckets (num_dst <= 131072)
constexpr int CHP = 2048;    // edges per chunk
constexpr int LDK = 136;     // 128 + 8 pad (bf16 elems)

typedef __attribute__((ext_vector_type(8))) short short8;
typedef __attribute__((ext_vector_type(4))) float float4v;

__device__ inline unsigned short f2bf(float f) {
    union { float f; unsigned u; } c; c.f = f;
    unsigned u = c.u;
    return (unsigned short)((u + 0x7FFFu + ((u >> 16) & 1u)) >> 16);  // RNE
}
__device__ inline float bf2f(unsigned short h) {
    union { unsigned u; float f; } c; c.u = (unsigned)h << 16;
    return c.f;
}

// ---------------- 1. x->bf16 + W->bf16^T ----------------
__global__ __launch_bounds__(256) void k_conv(const float* __restrict__ x,
                                              const float* __restrict__ Ws,
                                              const float* __restrict__ Wn,
                                              unsigned short* __restrict__ xb,
                                              unsigned short* __restrict__ WtG, long n4) {
    long tid = (long)blockIdx.x * 256 + threadIdx.x;
    if (tid < 2 * F * F) {
        int i = (int)tid;
        int n = i & 63, k = i >> 6;
        float v = (k < 64) ? Ws[k * 64 + n] : Wn[(k - 64) * 64 + n];
        WtG[n * 128 + k] = f2bf(v);
    }
    for (long i = tid; i < n4; i += (long)gridDim.x * 256) {
        float4 v = ((const float4*)x)[i];
        ushort4 o;
        o.x = f2bf(v.x); o.y = f2bf(v.y); o.z = f2bf(v.z); o.w = f2bf(v.w);
        ((ushort4*)xb)[i] = o;
    }
}

// ---------------- 2. per-chunk bucket counts ----------------
__global__ __launch_bounds__(256) void k_count(const int* __restrict__ dst,
                                               int* __restrict__ cnt, int n_edges) {
    __shared__ int hist[MAXNB];
    int t = threadIdx.x;
    int c = blockIdx.x;
    int e0 = c * CHP, e1 = min(e0 + CHP, n_edges);
    for (int i = t; i < MAXNB; i += 256) hist[i] = 0;
    __syncthreads();
    for (int e = e0 + t; e < e1; e += 256) atomicAdd(&hist[dst[e] >> 8], 1);
    __syncthreads();
    for (int i = t; i < MAXNB; i += 256) cnt[c * MAXNB + i] = hist[i];
}

// ---------------- 3. column scan + bucket scan ----------------
__global__ __launch_bounds__(MAXNB) void k_scan(int* __restrict__ cnt,   // in-place -> pref
                                                int* __restrict__ bstart,
                                                int nchunk, int nb, int n_edges) {
    __shared__ int buf[MAXNB];
    int t = threadIdx.x;
    int acc = 0;
    for (int c = 0; c < nchunk; ++c) {
        int v = cnt[c * MAXNB + t];
        cnt[c * MAXNB + t] = acc;   // exclusive prefix over chunks for bucket t
        acc += v;
    }
    buf[t] = acc;                   // bucket total
    __syncthreads();
    for (int off = 1; off < MAXNB; off <<= 1) {
        int tv = (t >= off) ? buf[t - off] : 0;
        __syncthreads();
        buf[t] += tv;
        __syncthreads();
    }
    int ex = buf[t] - acc;
    if (t < nb) bstart[t] = ex;
    if (t == MAXNB - 1) bstart[nb] = buf[MAXNB - 1];   // == n_edges
}

// ---------------- 4. place edges (deterministic) ----------------
__global__ __launch_bounds__(256) void k_place(const int* __restrict__ src,
                                               const int* __restrict__ dst,
                                               const int* __restrict__ cnt,     // pref
                                               const int* __restrict__ bstart,
                                               unsigned* __restrict__ pay, int n_edges) {
    __shared__ int lcur[MAXNB];
    int t = threadIdx.x;
    int c = blockIdx.x;
    int e0 = c * CHP, e1 = min(e0 + CHP, n_edges);
    for (int i = t; i < MAXNB; i += 256) lcur[i] = 0;
    __syncthreads();
    const int* pref = &cnt[c * MAXNB];
    for (int e = e0 + t; e < e1; e += 256) {
        int d = dst[e];
        int b = d >> 8;
        int rank = atomicAdd(&lcur[b], 1);
        int pos = bstart[b] + pref[b] + rank;
        pay[pos] = ((unsigned)src[e] << 8) | (unsigned)(d & 255);
    }
}

// ---------------- 5. per-bucket exact CSR ----------------
__global__ __launch_bounds__(512) void k_csr(const unsigned* __restrict__ pay,
                                             const int* __restrict__ bstart,
                                             int* __restrict__ row_start,
                                             int* __restrict__ csr,
                                             int num_dst, int n_edges, int nb) {
    __shared__ int hist[BROWS];
    __shared__ int scn[BROWS];
    int t = threadIdx.x;
    int b = blockIdx.x;
    int s0 = bstart[b], s1 = bstart[b + 1];
    if (t < BROWS) hist[t] = 0;
    __syncthreads();
    for (int i = s0 + t; i < s1; i += 512) atomicAdd(&hist[pay[i] & 255], 1);
    __syncthreads();
    int v = 0;
    if (t < BROWS) { v = hist[t]; scn[t] = v; }
    __syncthreads();
    for (int off = 1; off < BROWS; off <<= 1) {
        int tv = 0;
        if (t < BROWS && t >= off) tv = scn[t - off];
        __syncthreads();
        if (t < BROWS) scn[t] += tv;
        __syncthreads();
    }
    int r0 = b * BROWS;
    if (t < BROWS) {
        int excl = scn[t] - v;
        if (r0 + t < num_dst) row_start[r0 + t] = s0 + excl;
        hist[t] = excl;   // reuse as cursor
    }
    if (b == nb - 1 && t == 0) row_start[num_dst] = n_edges;
    __syncthreads();
    for (int i = s0 + t; i < s1; i += 512) {
        unsigned p = pay[i];
        int pos = atomicAdd(&hist[p & 255], 1);
        csr[s0 + pos] = (int)(p >> 8);
    }
}

// ---------------- 6. aggregate: wave per row, 16 lanes/edge ushort4 ----------------
__global__ __launch_bounds__(256) void k_aggregate(const unsigned short* __restrict__ xb,
                                                   const int* __restrict__ row_start,
                                                   const int* __restrict__ csr,
                                                   unsigned short* __restrict__ hb, int num_dst) {
    int lane = threadIdx.x & 63;
    int r = (blockIdx.x * 256 + threadIdx.x) >> 6;
    if (r >= num_dst) return;
    int g = lane >> 4;          // edge slot within group of 4
    int c4 = (lane & 15) * 4;   // feature quad
    int s0 = row_start[r], s1 = row_start[r + 1];
    int rem = s1 - s0;
    float4 accA = make_float4(0.f, 0.f, 0.f, 0.f);
    float4 accB = make_float4(0.f, 0.f, 0.f, 0.f);
    for (int base = 0; base < rem; base += 64) {
        int sid = (base + lane < rem) ? csr[s0 + base + lane] : 0;
        int n = min(64, rem - base);
        int i = 0;
        for (; i + 7 < n; i += 8) {
            int e0 = __shfl(sid, i + g);
            int e1 = __shfl(sid, i + 4 + g);
            ushort4 u0 = *(const ushort4*)&xb[(long)e0 * F + c4];
            ushort4 u1 = *(const ushort4*)&xb[(long)e1 * F + c4];
            accA.x += bf2f(u0.x); accA.y += bf2f(u0.y); accA.z += bf2f(u0.z); accA.w += bf2f(u0.w);
            accB.x += bf2f(u1.x); accB.y += bf2f(u1.y); accB.z += bf2f(u1.z); accB.w += bf2f(u1.w);
        }
        for (; i < n; i += 4) {
            int eslot = i + g;
            int e = __shfl(sid, eslot);
            if (eslot < n) {
                ushort4 u = *(const ushort4*)&xb[(long)e * F + c4];
                accA.x += bf2f(u.x); accA.y += bf2f(u.y); accA.z += bf2f(u.z); accA.w += bf2f(u.w);
            }
        }
    }
    float4 acc;
    acc.x = accA.x + accB.x; acc.y = accA.y + accB.y;
    acc.z = accA.z + accB.z; acc.w = accA.w + accB.w;
    acc.x += __shfl_xor(acc.x, 16); acc.y += __shfl_xor(acc.y, 16);
    acc.z += __shfl_xor(acc.z, 16); acc.w += __shfl_xor(acc.w, 16);
    acc.x += __shfl_xor(acc.x, 32); acc.y += __shfl_xor(acc.y, 32);
    acc.z += __shfl_xor(acc.z, 32); acc.w += __shfl_xor(acc.w, 32);
    if (lane < 16) {
        float inv = 1.0f / fmaxf((float)rem, 1.0f);
        ushort4 o;
        o.x = f2bf(acc.x * inv); o.y = f2bf(acc.y * inv);
        o.z = f2bf(acc.z * inv); o.w = f2bf(acc.w * inv);
        *(ushort4*)&hb[(long)r * F + c4] = o;
    }
}

// ---------------- 7. fused dual-GEMM, bf16 MFMA ----------------
__global__ __launch_bounds__(256) void k_gemm_mfma(
    const unsigned short* __restrict__ xb, const unsigned short* __restrict__ hb,
    const unsigned short* __restrict__ WtG,   // [n][k=0..127] bf16, pre-transposed
    const float* __restrict__ b, float* __restrict__ out, int num_dst)
{
    __shared__ __align__(16) unsigned short Atile[64 * LDK];
    __shared__ __align__(16) unsigned short Wt[64 * LDK];
    int t = threadIdx.x;
    int row0 = blockIdx.x * 64;

    for (int i = t; i < 64 * 16; i += 256) {
        int r = i >> 4, s = i & 15;
        *(short8*)&Wt[r * LDK + s * 8] = *(const short8*)&WtG[r * 128 + s * 8];
        int g = row0 + r;
        short8 v = {0, 0, 0, 0, 0, 0, 0, 0};
        if (g < num_dst)
            v = (s < 8) ? *(const short8*)&xb[(long)g * F + s * 8]
                        : *(const short8*)&hb[(long)g * F + (s - 8) * 8];
        *(short8*)&Atile[r * LDK + s * 8] = v;
    }
    __syncthreads();

    int lane = t & 63;
    int wave = t >> 6;
    int m = lane & 15;
    int quad = lane >> 4;
    const unsigned short* arow = &Atile[(wave * 16 + m) * LDK + quad * 8];

    float4v acc[4];
#pragma unroll
    for (int nt = 0; nt < 4; ++nt) acc[nt] = (float4v){0.f, 0.f, 0.f, 0.f};

#pragma unroll
    for (int kb = 0; kb < 4; ++kb) {
        short8 a = *(const short8*)(arow + kb * 32);
#pragma unroll
        for (int nt = 0; nt < 4; ++nt) {
            short8 bf = *(const short8*)&Wt[(nt * 16 + m) * LDK + quad * 8 + kb * 32];
            acc[nt] = __builtin_amdgcn_mfma_f32_16x16x32_bf16(a, bf, acc[nt], 0, 0, 0);
        }
    }

    int gr_base = row0 + wave * 16 + quad * 4;
#pragma unroll
    for (int nt = 0; nt < 4; ++nt) {
        int col = nt * 16 + m;
        float bias = b[col];
#pragma unroll
        for (int rg = 0; rg < 4; ++rg) {
            int g = gr_base + rg;
            if (g < num_dst) out[(long)g * F + col] = fmaxf(acc[nt][rg] + bias, 0.0f);
        }
    }
}

// ---------------- fallback (R0, proven) ----------------
__global__ __launch_bounds__(256) void k_scatter(const float* __restrict__ x, const int* __restrict__ src,
                                                 const int* __restrict__ dst, float* __restrict__ summed,
                                                 float* __restrict__ degf, int n_edges) {
    long tid = (long)blockIdx.x * 256 + threadIdx.x;
    int e = (int)(tid >> 6);
    if (e >= n_edges) return;
    int f = threadIdx.x & 63;
    atomicAdd(&summed[(long)dst[e] * F + f], x[(long)src[e] * F + f]);
    if (f == 0) atomicAdd(&degf[dst[e]], 1.0f);
}

__global__ __launch_bounds__(256) void k_gemm_shfl(
    const float* __restrict__ x, const float* __restrict__ Ws, const float* __restrict__ Wn,
    const float* __restrict__ b, const float* __restrict__ degf, float* inout, int num_dst)
{
    __shared__ float Wl[2 * F * F];
    for (int i = threadIdx.x; i < F * F; i += 256) { Wl[i] = Ws[i]; Wl[F * F + i] = Wn[i]; }
    __syncthreads();
    int lane = threadIdx.x & 63;
    int r = (blockIdx.x * 256 + threadIdx.x) >> 6;
    if (r >= num_dst) return;
    float xv = x[(long)r * F + lane];
    float hv = inout[(long)r * F + lane] / fmaxf(degf[r], 1.0f);
    float acc = b[lane];
#pragma unroll
    for (int k = 0; k < F; ++k) {
        acc += __shfl(xv, k) * Wl[k * F + lane];
        acc += __shfl(hv, k) * Wl[(F + k) * F + lane];
    }
    inout[(long)r * F + lane] = fmaxf(acc, 0.0f);
}

// ---------------- launch ----------------
extern "C" void kernel_launch(void* const* d_in, const int* in_sizes, int n_in,
                              void* d_out, int out_size, void* d_ws, size_t ws_size,
                              hipStream_t stream) {
    const float* x  = (const float*)d_in[0];
    const float* Ws = (const float*)d_in[1];
    const float* Wn = (const float*)d_in[2];
    const float* b  = (const float*)d_in[3];
    const int* src  = (const int*)d_in[4];
    const int* dst  = (const int*)d_in[5];
    int n_edges = in_sizes[4];
    int num_dst = out_size / F;
    float* out = (float*)d_out;

    int nchunk = (n_edges + CHP - 1) / CHP;
    int nb = (num_dst + BROWS - 1) / BROWS;

    char* ws = (char*)d_ws;
    size_t off = 0;
    auto alloc = [&](size_t bytes) { char* p = ws + off; off = (off + bytes + 255) & ~(size_t)255; return p; };
    unsigned short* xb  = (unsigned short*)alloc((size_t)num_dst * F * 2);
    unsigned short* hb  = (unsigned short*)alloc((size_t)num_dst * F * 2);
    unsigned* pay       = (unsigned*)alloc((size_t)n_edges * 4);
    int* csr            = (int*)alloc((size_t)n_edges * 4);
    int* row_start      = (int*)alloc((size_t)(num_dst + 1) * 4);
    unsigned short* WtG = (unsigned short*)alloc(2 * F * F * 2);
    int* cnt            = (int*)alloc((size_t)nchunk * MAXNB * 4);
    int* bstart         = (int*)alloc((MAXNB + 1) * 4);
    bool big_ws = (off <= ws_size) && (nb <= MAXNB);

    if (big_ws) {
        long n4 = (long)num_dst * F / 4;
        k_conv<<<2048, 256, 0, stream>>>(x, Ws, Wn, xb, WtG, n4);
        k_count<<<nchunk, 256, 0, stream>>>(dst, cnt, n_edges);
        k_scan<<<1, MAXNB, 0, stream>>>(cnt, bstart, nchunk, nb, n_edges);
        k_place<<<nchunk, 256, 0, stream>>>(src, dst, cnt, bstart, pay, n_edges);
        k_csr<<<nb, 512, 0, stream>>>(pay, bstart, row_start, csr, num_dst, n_edges, nb);
        k_aggregate<<<(num_dst + 3) / 4, 256, 0, stream>>>(xb, row_start, csr, hb, num_dst);
        k_gemm_mfma<<<(num_dst + 63) / 64, 256, 0, stream>>>(xb, hb, WtG, b, out, num_dst);
    } else {
        float* degf = (float*)d_ws;
        (void)hipMemsetAsync(d_out, 0, (size_t)out_size * sizeof(float), stream);
        (void)hipMemsetAsync(degf, 0, (size_t)num_dst * sizeof(float), stream);
        long tt = (long)n_edges * 64;
        k_scatter<<<(int)((tt + 255) / 256), 256, 0, stream>>>(x, src, dst, out, degf, n_edges);
        k_gemm_shfl<<<(num_dst + 3) / 4, 256, 0, stream>>>(x, Ws, Wn, b, degf, out, num_dst);
    }
}

// Round 8
// 170.519 us; speedup vs baseline: 1.6123x; 1.6123x over previous
//
#include <hip/hip_runtime.h>

// SAGE layer: out = relu(x @ W_self + (segment_sum(x[src], dst)/max(deg,1)) @ W_neigh + b)
//
// R7 = R6 with the serial 1-block k_scan (121us, latency-bound) split into:
//   k_scanA: wave per bucket, parallel column scan of cnt (489 chunks) -> per-chunk bases + btot
//   k_scanB: 1-block LDS scan of 512 bucket totals -> bstart
// Pipeline (8 dispatches, zero global atomics, no memsets on main path):
//   1. k_conv   2. k_count   3. k_scanA   4. k_scanB   5. k_place
//   6. k_csr    7. k_aggregate   8. k_gemm_mfma
// Fallback (small ws): R0 atomic scatter + shfl gemm.

constexpr int F = 64;
constexpr int BROWS = 256;   // dst rows per bucket
constexpr int MAXNB = 512;   // max buckets (num_dst <= 131072)
constexpr int CHP = 2048;    // edges per chunk
constexpr int LDK = 136;     // 128 + 8 pad (bf16 elems)

typedef __attribute__((ext_vector_type(8))) short short8;
typedef __attribute__((ext_vector_type(4))) float float4v;

__device__ inline unsigned short f2bf(float f) {
    union { float f; unsigned u; } c; c.f = f;
    unsigned u = c.u;
    return (unsigned short)((u + 0x7FFFu + ((u >> 16) & 1u)) >> 16);  // RNE
}
__device__ inline float bf2f(unsigned short h) {
    union { unsigned u; float f; } c; c.u = (unsigned)h << 16;
    return c.f;
}

// ---------------- 1. x->bf16 + W->bf16^T ----------------
__global__ __launch_bounds__(256) void k_conv(const float* __restrict__ x,
                                              const float* __restrict__ Ws,
                                              const float* __restrict__ Wn,
                                              unsigned short* __restrict__ xb,
                                              unsigned short* __restrict__ WtG, long n4) {
    long tid = (long)blockIdx.x * 256 + threadIdx.x;
    if (tid < 2 * F * F) {
        int i = (int)tid;
        int n = i & 63, k = i >> 6;
        float v = (k < 64) ? Ws[k * 64 + n] : Wn[(k - 64) * 64 + n];
        WtG[n * 128 + k] = f2bf(v);
    }
    for (long i = tid; i < n4; i += (long)gridDim.x * 256) {
        float4 v = ((const float4*)x)[i];
        ushort4 o;
        o.x = f2bf(v.x); o.y = f2bf(v.y); o.z = f2bf(v.z); o.w = f2bf(v.w);
        ((ushort4*)xb)[i] = o;
    }
}

// ---------------- 2. per-chunk bucket counts ----------------
__global__ __launch_bounds__(256) void k_count(const int* __restrict__ dst,
                                               int* __restrict__ cnt, int n_edges) {
    __shared__ int hist[MAXNB];
    int t = threadIdx.x;
    int c = blockIdx.x;
    int e0 = c * CHP, e1 = min(e0 + CHP, n_edges);
    for (int i = t; i < MAXNB; i += 256) hist[i] = 0;
    __syncthreads();
    for (int e = e0 + t; e < e1; e += 256) atomicAdd(&hist[dst[e] >> 8], 1);
    __syncthreads();
    for (int i = t; i < MAXNB; i += 256) cnt[c * MAXNB + i] = hist[i];
}

// ---------------- 3a. parallel column scan: wave per bucket ----------------
__global__ __launch_bounds__(512) void k_scanA(int* __restrict__ cnt,   // in-place -> pref
                                               int* __restrict__ btot, int nchunk) {
    int b = (blockIdx.x * 512 + threadIdx.x) >> 6;   // bucket = global wave id
    int lane = threadIdx.x & 63;
    if (b >= MAXNB) return;
    int per = (nchunk + 63) / 64;                    // chunks per lane (<=16 for nchunk<=1024)
    int c0 = lane * per;
    int vals[16];
    int lsum = 0;
#pragma unroll
    for (int i = 0; i < 16; ++i) {
        if (i < per) {
            int c = c0 + i;
            int v = (c < nchunk) ? cnt[(long)c * MAXNB + b] : 0;
            vals[i] = v; lsum += v;
        }
    }
    // wave inclusive scan of per-lane sums
    int incl = lsum;
    for (int off = 1; off < 64; off <<= 1) {
        int o = __shfl_up(incl, off);
        if (lane >= off) incl += o;
    }
    int run = incl - lsum;   // exclusive base for this lane's first chunk
#pragma unroll
    for (int i = 0; i < 16; ++i) {
        if (i < per) {
            int c = c0 + i;
            if (c < nchunk) { cnt[(long)c * MAXNB + b] = run; run += vals[i]; }
        }
    }
    int tot = __shfl(incl, 63);
    if (lane == 0) btot[b] = tot;
}

// ---------------- 3b. scan bucket totals ----------------
__global__ __launch_bounds__(MAXNB) void k_scanB(const int* __restrict__ btot,
                                                 int* __restrict__ bstart, int nb) {
    __shared__ int buf[MAXNB];
    int t = threadIdx.x;
    int v = btot[t];
    buf[t] = v; __syncthreads();
    for (int off = 1; off < MAXNB; off <<= 1) {
        int tv = (t >= off) ? buf[t - off] : 0;
        __syncthreads();
        buf[t] += tv;
        __syncthreads();
    }
    int ex = buf[t] - v;
    if (t < nb) bstart[t] = ex;
    if (t == MAXNB - 1) bstart[nb] = buf[MAXNB - 1];
}

// ---------------- 4. place edges (deterministic) ----------------
__global__ __launch_bounds__(256) void k_place(const int* __restrict__ src,
                                               const int* __restrict__ dst,
                                               const int* __restrict__ cnt,     // pref
                                               const int* __restrict__ bstart,
                                               unsigned* __restrict__ pay, int n_edges) {
    __shared__ int lcur[MAXNB];
    int t = threadIdx.x;
    int c = blockIdx.x;
    int e0 = c * CHP, e1 = min(e0 + CHP, n_edges);
    for (int i = t; i < MAXNB; i += 256) lcur[i] = 0;
    __syncthreads();
    const int* pref = &cnt[(long)c * MAXNB];
    for (int e = e0 + t; e < e1; e += 256) {
        int d = dst[e];
        int b = d >> 8;
        int rank = atomicAdd(&lcur[b], 1);
        int pos = bstart[b] + pref[b] + rank;
        pay[pos] = ((unsigned)src[e] << 8) | (unsigned)(d & 255);
    }
}

// ---------------- 5. per-bucket exact CSR ----------------
__global__ __launch_bounds__(512) void k_csr(const unsigned* __restrict__ pay,
                                             const int* __restrict__ bstart,
                                             int* __restrict__ row_start,
                                             int* __restrict__ csr,
                                             int num_dst, int n_edges, int nb) {
    __shared__ int hist[BROWS];
    __shared__ int scn[BROWS];
    int t = threadIdx.x;
    int b = blockIdx.x;
    int s0 = bstart[b], s1 = bstart[b + 1];
    if (t < BROWS) hist[t] = 0;
    __syncthreads();
    for (int i = s0 + t; i < s1; i += 512) atomicAdd(&hist[pay[i] & 255], 1);
    __syncthreads();
    int v = 0;
    if (t < BROWS) { v = hist[t]; scn[t] = v; }
    __syncthreads();
    for (int off = 1; off < BROWS; off <<= 1) {
        int tv = 0;
        if (t < BROWS && t >= off) tv = scn[t - off];
        __syncthreads();
        if (t < BROWS) scn[t] += tv;
        __syncthreads();
    }
    int r0 = b * BROWS;
    if (t < BROWS) {
        int excl = scn[t] - v;
        if (r0 + t < num_dst) row_start[r0 + t] = s0 + excl;
        hist[t] = excl;   // reuse as cursor
    }
    if (b == nb - 1 && t == 0) row_start[num_dst] = n_edges;
    __syncthreads();
    for (int i = s0 + t; i < s1; i += 512) {
        unsigned p = pay[i];
        int pos = atomicAdd(&hist[p & 255], 1);
        csr[s0 + pos] = (int)(p >> 8);
    }
}

// ---------------- 6. aggregate: wave per row, 16 lanes/edge ushort4 ----------------
__global__ __launch_bounds__(256) void k_aggregate(const unsigned short* __restrict__ xb,
                                                   const int* __restrict__ row_start,
                                                   const int* __restrict__ csr,
                                                   unsigned short* __restrict__ hb, int num_dst) {
    int lane = threadIdx.x & 63;
    int r = (blockIdx.x * 256 + threadIdx.x) >> 6;
    if (r >= num_dst) return;
    int g = lane >> 4;          // edge slot within group of 4
    int c4 = (lane & 15) * 4;   // feature quad
    int s0 = row_start[r], s1 = row_start[r + 1];
    int rem = s1 - s0;
    float4 accA = make_float4(0.f, 0.f, 0.f, 0.f);
    float4 accB = make_float4(0.f, 0.f, 0.f, 0.f);
    for (int base = 0; base < rem; base += 64) {
        int sid = (base + lane < rem) ? csr[s0 + base + lane] : 0;
        int n = min(64, rem - base);
        int i = 0;
        for (; i + 7 < n; i += 8) {
            int e0 = __shfl(sid, i + g);
            int e1 = __shfl(sid, i + 4 + g);
            ushort4 u0 = *(const ushort4*)&xb[(long)e0 * F + c4];
            ushort4 u1 = *(const ushort4*)&xb[(long)e1 * F + c4];
            accA.x += bf2f(u0.x); accA.y += bf2f(u0.y); accA.z += bf2f(u0.z); accA.w += bf2f(u0.w);
            accB.x += bf2f(u1.x); accB.y += bf2f(u1.y); accB.z += bf2f(u1.z); accB.w += bf2f(u1.w);
        }
        for (; i < n; i += 4) {
            int eslot = i + g;
            int e = __shfl(sid, eslot);
            if (eslot < n) {
                ushort4 u = *(const ushort4*)&xb[(long)e * F + c4];
                accA.x += bf2f(u.x); accA.y += bf2f(u.y); accA.z += bf2f(u.z); accA.w += bf2f(u.w);
            }
        }
    }
    float4 acc;
    acc.x = accA.x + accB.x; acc.y = accA.y + accB.y;
    acc.z = accA.z + accB.z; acc.w = accA.w + accB.w;
    acc.x += __shfl_xor(acc.x, 16); acc.y += __shfl_xor(acc.y, 16);
    acc.z += __shfl_xor(acc.z, 16); acc.w += __shfl_xor(acc.w, 16);
    acc.x += __shfl_xor(acc.x, 32); acc.y += __shfl_xor(acc.y, 32);
    acc.z += __shfl_xor(acc.z, 32); acc.w += __shfl_xor(acc.w, 32);
    if (lane < 16) {
        float inv = 1.0f / fmaxf((float)rem, 1.0f);
        ushort4 o;
        o.x = f2bf(acc.x * inv); o.y = f2bf(acc.y * inv);
        o.z = f2bf(acc.z * inv); o.w = f2bf(acc.w * inv);
        *(ushort4*)&hb[(long)r * F + c4] = o;
    }
}

// ---------------- 7. fused dual-GEMM, bf16 MFMA ----------------
__global__ __launch_bounds__(256) void k_gemm_mfma(
    const unsigned short* __restrict__ xb, const unsigned short* __restrict__ hb,
    const unsigned short* __restrict__ WtG,   // [n][k=0..127] bf16, pre-transposed
    const float* __restrict__ b, float* __restrict__ out, int num_dst)
{
    __shared__ __align__(16) unsigned short Atile[64 * LDK];
    __shared__ __align__(16) unsigned short Wt[64 * LDK];
    int t = threadIdx.x;
    int row0 = blockIdx.x * 64;

    for (int i = t; i < 64 * 16; i += 256) {
        int r = i >> 4, s = i & 15;
        *(short8*)&Wt[r * LDK + s * 8] = *(const short8*)&WtG[r * 128 + s * 8];
        int g = row0 + r;
        short8 v = {0, 0, 0, 0, 0, 0, 0, 0};
        if (g < num_dst)
            v = (s < 8) ? *(const short8*)&xb[(long)g * F + s * 8]
                        : *(const short8*)&hb[(long)g * F + (s - 8) * 8];
        *(short8*)&Atile[r * LDK + s * 8] = v;
    }
    __syncthreads();

    int lane = t & 63;
    int wave = t >> 6;
    int m = lane & 15;
    int quad = lane >> 4;
    const unsigned short* arow = &Atile[(wave * 16 + m) * LDK + quad * 8];

    float4v acc[4];
#pragma unroll
    for (int nt = 0; nt < 4; ++nt) acc[nt] = (float4v){0.f, 0.f, 0.f, 0.f};

#pragma unroll
    for (int kb = 0; kb < 4; ++kb) {
        short8 a = *(const short8*)(arow + kb * 32);
#pragma unroll
        for (int nt = 0; nt < 4; ++nt) {
            short8 bf = *(const short8*)&Wt[(nt * 16 + m) * LDK + quad * 8 + kb * 32];
            acc[nt] = __builtin_amdgcn_mfma_f32_16x16x32_bf16(a, bf, acc[nt], 0, 0, 0);
        }
    }

    int gr_base = row0 + wave * 16 + quad * 4;
#pragma unroll
    for (int nt = 0; nt < 4; ++nt) {
        int col = nt * 16 + m;
        float bias = b[col];
#pragma unroll
        for (int rg = 0; rg < 4; ++rg) {
            int g = gr_base + rg;
            if (g < num_dst) out[(long)g * F + col] = fmaxf(acc[nt][rg] + bias, 0.0f);
        }
    }
}

// ---------------- fallback (R0, proven) ----------------
__global__ __launch_bounds__(256) void k_scatter(const float* __restrict__ x, const int* __restrict__ src,
                                                 const int* __restrict__ dst, float* __restrict__ summed,
                                                 float* __restrict__ degf, int n_edges) {
    long tid = (long)blockIdx.x * 256 + threadIdx.x;
    int e = (int)(tid >> 6);
    if (e >= n_edges) return;
    int f = threadIdx.x & 63;
    atomicAdd(&summed[(long)dst[e] * F + f], x[(long)src[e] * F + f]);
    if (f == 0) atomicAdd(&degf[dst[e]], 1.0f);
}

__global__ __launch_bounds__(256) void k_gemm_shfl(
    const float* __restrict__ x, const float* __restrict__ Ws, const float* __restrict__ Wn,
    const float* __restrict__ b, const float* __restrict__ degf, float* inout, int num_dst)
{
    __shared__ float Wl[2 * F * F];
    for (int i = threadIdx.x; i < F * F; i += 256) { Wl[i] = Ws[i]; Wl[F * F + i] = Wn[i]; }
    __syncthreads();
    int lane = threadIdx.x & 63;
    int r = (blockIdx.x * 256 + threadIdx.x) >> 6;
    if (r >= num_dst) return;
    float xv = x[(long)r * F + lane];
    float hv = inout[(long)r * F + lane] / fmaxf(degf[r], 1.0f);
    float acc = b[lane];
#pragma unroll
    for (int k = 0; k < F; ++k) {
        acc += __shfl(xv, k) * Wl[k * F + lane];
        acc += __shfl(hv, k) * Wl[(F + k) * F + lane];
    }
    inout[(long)r * F + lane] = fmaxf(acc, 0.0f);
}

// ---------------- launch ----------------
extern "C" void kernel_launch(void* const* d_in, const int* in_sizes, int n_in,
                              void* d_out, int out_size, void* d_ws, size_t ws_size,
                              hipStream_t stream) {
    const float* x  = (const float*)d_in[0];
    const float* Ws = (const float*)d_in[1];
    const float* Wn = (const float*)d_in[2];
    const float* b  = (const float*)d_in[3];
    const int* src  = (const int*)d_in[4];
    const int* dst  = (const int*)d_in[5];
    int n_edges = in_sizes[4];
    int num_dst = out_size / F;
    float* out = (float*)d_out;

    int nchunk = (n_edges + CHP - 1) / CHP;
    int nb = (num_dst + BROWS - 1) / BROWS;

    char* ws = (char*)d_ws;
    size_t off = 0;
    auto alloc = [&](size_t bytes) { char* p = ws + off; off = (off + bytes + 255) & ~(size_t)255; return p; };
    unsigned short* xb  = (unsigned short*)alloc((size_t)num_dst * F * 2);
    unsigned short* hb  = (unsigned short*)alloc((size_t)num_dst * F * 2);
    unsigned* pay       = (unsigned*)alloc((size_t)n_edges * 4);
    int* csr            = (int*)alloc((size_t)n_edges * 4);
    int* row_start      = (int*)alloc((size_t)(num_dst + 1) * 4);
    unsigned short* WtG = (unsigned short*)alloc(2 * F * F * 2);
    int* cnt            = (int*)alloc((size_t)nchunk * MAXNB * 4);
    int* btot           = (int*)alloc(MAXNB * 4);
    int* bstart         = (int*)alloc((MAXNB + 1) * 4);
    bool big_ws = (off <= ws_size) && (nb <= MAXNB) && (nchunk <= 1024);

    if (big_ws) {
        long n4 = (long)num_dst * F / 4;
        k_conv<<<2048, 256, 0, stream>>>(x, Ws, Wn, xb, WtG, n4);
        k_count<<<nchunk, 256, 0, stream>>>(dst, cnt, n_edges);
        k_scanA<<<(MAXNB * 64 + 511) / 512, 512, 0, stream>>>(cnt, btot, nchunk);
        k_scanB<<<1, MAXNB, 0, stream>>>(btot, bstart, nb);
        k_place<<<nchunk, 256, 0, stream>>>(src, dst, cnt, bstart, pay, n_edges);
        k_csr<<<nb, 512, 0, stream>>>(pay, bstart, row_start, csr, num_dst, n_edges, nb);
        k_aggregate<<<(num_dst + 3) / 4, 256, 0, stream>>>(xb, row_start, csr, hb, num_dst);
        k_gemm_mfma<<<(num_dst + 63) / 64, 256, 0, stream>>>(xb, hb, WtG, b, out, num_dst);
    } else {
        float* degf = (float*)d_ws;
        (void)hipMemsetAsync(d_out, 0, (size_t)out_size * sizeof(float), stream);
        (void)hipMemsetAsync(degf, 0, (size_t)num_dst * sizeof(float), stream);
        long tt = (long)n_edges * 64;
        k_scatter<<<(int)((tt + 255) / 256), 256, 0, stream>>>(x, src, dst, out, degf, n_edges);
        k_gemm_shfl<<<(num_dst + 3) / 4, 256, 0, stream>>>(x, Ws, Wn, b, degf, out, num_dst);
    }
}